// Round 1
// baseline (3503.721 us; speedup 1.0000x reference)
//
#include <hip/hip_runtime.h>
#include <hip/hip_bf16.h>

// Problem constants (reference: B=2, T=2048, C=2048, NH=16, NKV=4, HD=128, GATE_CH=12)
#define BB   2
#define TT   2048
#define CC   2048
#define NHq  16
#define NKVq 4
#define HDq  128
#define ROWS (BB*TT)          // 4096
#define NQKV (NHq*HDq + 2*NKVq*HDq)  // 3072

using bf16 = __hip_bfloat16;
using short8 = __attribute__((ext_vector_type(8))) short;
using f32x4  = __attribute__((ext_vector_type(4))) float;

#define MFMA16(a,b,c) __builtin_amdgcn_mfma_f32_16x16x32_bf16((a),(b),(c),0,0,0)

// ---------------- cast fp32 -> bf16, 4 elems/thread ----------------
__global__ void cast_bf16(const float* __restrict__ in, bf16* __restrict__ out, int n4) {
    int i = blockIdx.x * 256 + threadIdx.x;
    if (i < n4) {
        float4 v = reinterpret_cast<const float4*>(in)[i];
        ushort4 o;
        o.x = __bfloat16_as_ushort(__float2bfloat16(v.x));
        o.y = __bfloat16_as_ushort(__float2bfloat16(v.y));
        o.z = __bfloat16_as_ushort(__float2bfloat16(v.z));
        o.w = __bfloat16_as_ushort(__float2bfloat16(v.w));
        reinterpret_cast<ushort4*>(out)[i] = o;
    }
}

// ---------------- bf16 MFMA GEMM:  C[M,N] = A[M,K] * B[N,K]^T ----------------
// 128x128 tile, 4 waves (2x2), each wave 64x64 = 4x4 fragments of 16x16x32.
// OUT_F32: write float, else bf16.
template<int OUT_F32>
__global__ __launch_bounds__(256) void gemm_bt(const bf16* __restrict__ A,
                                               const bf16* __restrict__ B,
                                               void* __restrict__ Cp,
                                               int M, int N, int K) {
    const int bm = blockIdx.x * 128;
    const int bn = blockIdx.y * 128;
    const int tid = threadIdx.x;
    const int lane = tid & 63;
    const int w = tid >> 6;
    const int wr = w >> 1, wc = w & 1;   // 2x2 waves of 64x64

    // +8 pad (40 bf16 = 80B row stride) -> 2-way-max bank aliasing on b128 reads (free)
    __shared__ __align__(16) bf16 As[128][40];
    __shared__ __align__(16) bf16 Bs[128][40];

    f32x4 acc[4][4];
#pragma unroll
    for (int i = 0; i < 4; ++i)
#pragma unroll
        for (int j = 0; j < 4; ++j) acc[i][j] = f32x4{0.f, 0.f, 0.f, 0.f};

    const int lrow = tid >> 2;        // 0..63
    const int lcol = (tid & 3) * 8;   // 0,8,16,24

    for (int k0 = 0; k0 < K; k0 += 32) {
        __syncthreads();
#pragma unroll
        for (int p = 0; p < 2; ++p) {
            int r = p * 64 + lrow;
            *reinterpret_cast<short8*>(&As[r][lcol]) =
                *reinterpret_cast<const short8*>(&A[(size_t)(bm + r) * K + k0 + lcol]);
            *reinterpret_cast<short8*>(&Bs[r][lcol]) =
                *reinterpret_cast<const short8*>(&B[(size_t)(bn + r) * K + k0 + lcol]);
        }
        __syncthreads();

        const int fr = lane & 15;          // fragment row
        const int kq = (lane >> 4) * 8;    // k sub-offset
        short8 af[4], bfr[4];
#pragma unroll
        for (int m = 0; m < 4; ++m)
            af[m] = *reinterpret_cast<const short8*>(&As[wr * 64 + m * 16 + fr][kq]);
#pragma unroll
        for (int n = 0; n < 4; ++n)
            bfr[n] = *reinterpret_cast<const short8*>(&Bs[wc * 64 + n * 16 + fr][kq]);
#pragma unroll
        for (int m = 0; m < 4; ++m)
#pragma unroll
            for (int n = 0; n < 4; ++n)
                acc[m][n] = MFMA16(af[m], bfr[n], acc[m][n]);
    }

    // C/D layout (m89-verified): col = lane&15, row = (lane>>4)*4 + reg
    const int cr = (lane >> 4) * 4;
    const int cc = lane & 15;
#pragma unroll
    for (int m = 0; m < 4; ++m)
#pragma unroll
        for (int n = 0; n < 4; ++n) {
            int row = bm + wr * 64 + m * 16 + cr;
            int col = bn + wc * 64 + n * 16 + cc;
#pragma unroll
            for (int j = 0; j < 4; ++j) {
                float v = acc[m][n][j];
                if (OUT_F32) ((float*)Cp)[(size_t)(row + j) * N + col] = v;
                else         ((bf16*)Cp)[(size_t)(row + j) * N + col] = __float2bfloat16(v);
            }
        }
}

// ---------------- postproc: gate+ve add on V, RoPE+RMSNorm on Q,K (in place) ----------------
// one block per (b,t) row; qkv row layout: [q 0..2047 | k 2048..2559 | v 2560..3071]
__global__ __launch_bounds__(256) void postproc(const float* __restrict__ x,
                                                const float* __restrict__ ve,
                                                const float* __restrict__ cosb,
                                                const float* __restrict__ sinb,
                                                const float* __restrict__ Wgate,
                                                bf16* __restrict__ qkv) {
    const int row = blockIdx.x;            // b*T + t
    const int t = row & (TT - 1);
    const int tid = threadIdx.x;
    __shared__ float gate_s[NKVq];
    if (tid < NKVq) {
        float g = 0.f;
#pragma unroll
        for (int c = 0; c < 12; ++c) g += x[(size_t)row * CC + c] * Wgate[tid * 12 + c];
        gate_s[tid] = 3.0f / (1.0f + __expf(-g));
    }
    __syncthreads();

    bf16* qkvr = qkv + (size_t)row * NQKV;

    // v += gate * ve   (512 elems, 2/thread)
#pragma unroll
    for (int i = 0; i < 2; ++i) {
        int idx = tid + i * 256;
        float v = __bfloat162float(qkvr[2 * CC / 2 + 512 + idx]); // 2560 + idx
        v += gate_s[idx >> 7] * ve[(size_t)row * 512 + idx];
        qkvr[2560 + idx] = __float2bfloat16(v);
    }

    // RoPE + RMSNorm: heads 0..15 = q, 16..19 = k. Wave w handles heads w, w+4, ...
    const int lane = tid & 63;
    const int w = tid >> 6;
    const float cv = cosb[(size_t)t * 64 + lane];
    const float sv = sinb[(size_t)t * 64 + lane];
    for (int hh = w; hh < NHq + NKVq; hh += 4) {
        int off = (hh < NHq) ? hh * HDq : 2048 + (hh - NHq) * HDq;
        float x1 = __bfloat162float(qkvr[off + lane]);
        float x2 = __bfloat162float(qkvr[off + 64 + lane]);
        float r1 =  x1 * cv + x2 * sv;
        float r2 = -x1 * sv + x2 * cv;
        float ss = r1 * r1 + r2 * r2;
#pragma unroll
        for (int m = 1; m < 64; m <<= 1) ss += __shfl_xor(ss, m);
        float sc = rsqrtf(ss * (1.0f / 128.0f) + 1e-6f) * 1.2f;
        qkvr[off + lane]      = __float2bfloat16(r1 * sc);
        qkvr[off + 64 + lane] = __float2bfloat16(r2 * sc);
    }
}

// ---------------- attention: one wave per (b,h,t) query row, online softmax ----------------
__global__ __launch_bounds__(256) void attn(const bf16* __restrict__ qkv,
                                            bf16* __restrict__ y,
                                            const int* __restrict__ winp) {
    const int gwave = blockIdx.x * 4 + (threadIdx.x >> 6);
    const int lane = threadIdx.x & 63;
    const int t = gwave & (TT - 1);
    const int bh = gwave >> 11;
    const int h = bh & (NHq - 1);
    const int b = bh >> 4;
    const int kvh = h >> 2;                 // rep = NH/NKV = 4
    const int window = winp[0];

    const bf16* qr = qkv + ((size_t)(b * TT + t)) * NQKV + h * HDq;
    const float q0 = __bfloat162float(qr[2 * lane]);
    const float q1 = __bfloat162float(qr[2 * lane + 1]);

    int s0 = t - window; if (s0 < 0) s0 = 0;
    float m = -1e30f, l = 0.f, a0 = 0.f, a1 = 0.f;
    const float scale = 0.08838834764831845f;   // 1/sqrt(128)

    const bf16* base = qkv + (size_t)b * TT * NQKV + 2048 + kvh * HDq;
    for (int s = s0; s <= t; ++s) {
        const bf16* kr = base + (size_t)s * NQKV;
        float d = __bfloat162float(kr[2 * lane]) * q0 + __bfloat162float(kr[2 * lane + 1]) * q1;
#pragma unroll
        for (int mm = 1; mm < 64; mm <<= 1) d += __shfl_xor(d, mm);
        float sc = d * scale;
        float nm = fmaxf(m, sc);
        float corr = __expf(m - nm);
        float p = __expf(sc - nm);
        m = nm;
        l = l * corr + p;
        const bf16* vr = kr + 512;
        a0 = a0 * corr + p * __bfloat162float(vr[2 * lane]);
        a1 = a1 * corr + p * __bfloat162float(vr[2 * lane + 1]);
    }
    float inv = 1.0f / l;
    bf16* yr = y + ((size_t)(b * TT + t)) * CC + h * HDq;
    yr[2 * lane]     = __float2bfloat16(a0 * inv);
    yr[2 * lane + 1] = __float2bfloat16(a1 * inv);
}

extern "C" void kernel_launch(void* const* d_in, const int* in_sizes, int n_in,
                              void* d_out, int out_size, void* d_ws, size_t ws_size,
                              hipStream_t stream) {
    const float* x     = (const float*)d_in[0];
    const float* ve    = (const float*)d_in[1];
    const float* cosb  = (const float*)d_in[2];
    const float* sinb  = (const float*)d_in[3];
    const float* Wq    = (const float*)d_in[4];
    const float* Wk    = (const float*)d_in[5];
    const float* Wv    = (const float*)d_in[6];
    const float* Wproj = (const float*)d_in[7];
    const float* Wgate = (const float*)d_in[8];
    const int*   winp  = (const int*)d_in[9];

    // workspace carve (bf16):
    //   xb    : ROWS*CC          (also reused as y after qkv GEMM is consumed)
    //   wqkvb : NQKV*CC          ([Wq;Wk;Wv] stacked, row-major K-contiguous)
    //   wprojb: CC*CC
    //   qkvb  : ROWS*NQKV
    // total = (8.39M + 6.29M + 4.19M + 12.58M) * 2B = 62.9 MB
    bf16* xb     = (bf16*)d_ws;
    bf16* wqkvb  = xb + (size_t)ROWS * CC;
    bf16* wprojb = wqkvb + (size_t)NQKV * CC;
    bf16* qkvb   = wprojb + (size_t)CC * CC;
    bf16* yb     = xb;   // alias: xb dead after qkv GEMM; attention runs later in stream order

    // 1) casts fp32 -> bf16
    {
        int n4;
        n4 = ROWS * CC / 4;      cast_bf16<<<(n4 + 255) / 256, 256, 0, stream>>>(x, xb, n4);
        n4 = NHq * HDq * CC / 4; cast_bf16<<<(n4 + 255) / 256, 256, 0, stream>>>(Wq, wqkvb, n4);
        n4 = NKVq * HDq * CC / 4;
        cast_bf16<<<(n4 + 255) / 256, 256, 0, stream>>>(Wk, wqkvb + (size_t)NHq * HDq * CC, n4);
        cast_bf16<<<(n4 + 255) / 256, 256, 0, stream>>>(Wv, wqkvb + (size_t)(NHq + NKVq) * HDq * CC, n4);
        n4 = CC * CC / 4;        cast_bf16<<<(n4 + 255) / 256, 256, 0, stream>>>(Wproj, wprojb, n4);
    }

    // 2) qkv = x @ [Wq;Wk;Wv]^T   (4096 x 3072)
    gemm_bt<0><<<dim3(ROWS / 128, NQKV / 128), 256, 0, stream>>>(xb, wqkvb, qkvb, ROWS, NQKV, CC);

    // 3) gate/ve add + RoPE + RMSNorm (in place on qkvb)
    postproc<<<ROWS, 256, 0, stream>>>(x, ve, cosb, sinb, Wgate, qkvb);

    // 4) sliding-window GQA attention -> yb (bf16)
    attn<<<BB * NHq * TT / 4, 256, 0, stream>>>(qkvb, yb, winp);

    // 5) out = y @ Wproj^T  (fp32 out)
    gemm_bt<1><<<dim3(ROWS / 128, CC / 128), 256, 0, stream>>>(yb, wprojb, d_out, ROWS, CC, CC);
}

// Round 2
// 293.944 us; speedup vs baseline: 11.9197x; 11.9197x over previous
//
#include <hip/hip_runtime.h>
#include <hip/hip_bf16.h>

// Problem constants (reference: B=2, T=2048, C=2048, NH=16, NKV=4, HD=128, GATE_CH=12)
#define BB   2
#define TT   2048
#define CC   2048
#define NHq  16
#define NKVq 4
#define HDq  128
#define ROWS (BB*TT)          // 4096
#define NQKV (NHq*HDq + 2*NKVq*HDq)  // 3072

using bf16 = __hip_bfloat16;
using short8 = __attribute__((ext_vector_type(8))) short;
using f32x4  = __attribute__((ext_vector_type(4))) float;

#define MFMA16(a,b,c) __builtin_amdgcn_mfma_f32_16x16x32_bf16((a),(b),(c),0,0,0)

// ---------------- cast fp32 -> bf16, 4 elems/thread ----------------
__global__ void cast_bf16(const float* __restrict__ in, bf16* __restrict__ out, int n4) {
    int i = blockIdx.x * 256 + threadIdx.x;
    if (i < n4) {
        float4 v = reinterpret_cast<const float4*>(in)[i];
        ushort4 o;
        o.x = __bfloat16_as_ushort(__float2bfloat16(v.x));
        o.y = __bfloat16_as_ushort(__float2bfloat16(v.y));
        o.z = __bfloat16_as_ushort(__float2bfloat16(v.z));
        o.w = __bfloat16_as_ushort(__float2bfloat16(v.w));
        reinterpret_cast<ushort4*>(out)[i] = o;
    }
}

// ---------------- bf16 MFMA GEMM:  C[M,N] = A[M,K] * B[N,K]^T ----------------
template<int OUT_F32>
__global__ __launch_bounds__(256) void gemm_bt(const bf16* __restrict__ A,
                                               const bf16* __restrict__ B,
                                               void* __restrict__ Cp,
                                               int M, int N, int K) {
    const int bm = blockIdx.x * 128;
    const int bn = blockIdx.y * 128;
    const int tid = threadIdx.x;
    const int lane = tid & 63;
    const int w = tid >> 6;
    const int wr = w >> 1, wc = w & 1;   // 2x2 waves of 64x64

    __shared__ __align__(16) bf16 As[128][40];
    __shared__ __align__(16) bf16 Bs[128][40];

    f32x4 acc[4][4];
#pragma unroll
    for (int i = 0; i < 4; ++i)
#pragma unroll
        for (int j = 0; j < 4; ++j) acc[i][j] = f32x4{0.f, 0.f, 0.f, 0.f};

    const int lrow = tid >> 2;        // 0..63
    const int lcol = (tid & 3) * 8;   // 0,8,16,24

    for (int k0 = 0; k0 < K; k0 += 32) {
        __syncthreads();
#pragma unroll
        for (int p = 0; p < 2; ++p) {
            int r = p * 64 + lrow;
            *reinterpret_cast<short8*>(&As[r][lcol]) =
                *reinterpret_cast<const short8*>(&A[(size_t)(bm + r) * K + k0 + lcol]);
            *reinterpret_cast<short8*>(&Bs[r][lcol]) =
                *reinterpret_cast<const short8*>(&B[(size_t)(bn + r) * K + k0 + lcol]);
        }
        __syncthreads();

        const int fr = lane & 15;
        const int kq = (lane >> 4) * 8;
        short8 af[4], bfr[4];
#pragma unroll
        for (int m = 0; m < 4; ++m)
            af[m] = *reinterpret_cast<const short8*>(&As[wr * 64 + m * 16 + fr][kq]);
#pragma unroll
        for (int n = 0; n < 4; ++n)
            bfr[n] = *reinterpret_cast<const short8*>(&Bs[wc * 64 + n * 16 + fr][kq]);
#pragma unroll
        for (int m = 0; m < 4; ++m)
#pragma unroll
            for (int n = 0; n < 4; ++n)
                acc[m][n] = MFMA16(af[m], bfr[n], acc[m][n]);
    }

    const int cr = (lane >> 4) * 4;
    const int cc = lane & 15;
#pragma unroll
    for (int m = 0; m < 4; ++m)
#pragma unroll
        for (int n = 0; n < 4; ++n) {
            int row = bm + wr * 64 + m * 16 + cr;
            int col = bn + wc * 64 + n * 16 + cc;
#pragma unroll
            for (int j = 0; j < 4; ++j) {
                float v = acc[m][n][j];
                if (OUT_F32) ((float*)Cp)[(size_t)(row + j) * N + col] = v;
                else         ((bf16*)Cp)[(size_t)(row + j) * N + col] = __float2bfloat16(v);
            }
        }
}

// ---------------- postproc: gate+ve add on V, RoPE+RMSNorm on Q,K (in place) ----------------
__global__ __launch_bounds__(256) void postproc(const float* __restrict__ x,
                                                const float* __restrict__ ve,
                                                const float* __restrict__ cosb,
                                                const float* __restrict__ sinb,
                                                const float* __restrict__ Wgate,
                                                bf16* __restrict__ qkv) {
    const int row = blockIdx.x;            // b*T + t
    const int t = row & (TT - 1);
    const int tid = threadIdx.x;
    __shared__ float gate_s[NKVq];
    if (tid < NKVq) {
        float g = 0.f;
#pragma unroll
        for (int c = 0; c < 12; ++c) g += x[(size_t)row * CC + c] * Wgate[tid * 12 + c];
        gate_s[tid] = 3.0f / (1.0f + __expf(-g));
    }
    __syncthreads();

    bf16* qkvr = qkv + (size_t)row * NQKV;

#pragma unroll
    for (int i = 0; i < 2; ++i) {
        int idx = tid + i * 256;
        float v = __bfloat162float(qkvr[2560 + idx]);
        v += gate_s[idx >> 7] * ve[(size_t)row * 512 + idx];
        qkvr[2560 + idx] = __float2bfloat16(v);
    }

    const int lane = tid & 63;
    const int w = tid >> 6;
    const float cv = cosb[(size_t)t * 64 + lane];
    const float sv = sinb[(size_t)t * 64 + lane];
    for (int hh = w; hh < NHq + NKVq; hh += 4) {
        int off = (hh < NHq) ? hh * HDq : 2048 + (hh - NHq) * HDq;
        float x1 = __bfloat162float(qkvr[off + lane]);
        float x2 = __bfloat162float(qkvr[off + 64 + lane]);
        float r1 =  x1 * cv + x2 * sv;
        float r2 = -x1 * sv + x2 * cv;
        float ss = r1 * r1 + r2 * r2;
#pragma unroll
        for (int m = 1; m < 64; m <<= 1) ss += __shfl_xor(ss, m);
        float sc = rsqrtf(ss * (1.0f / 128.0f) + 1e-6f) * 1.2f;
        qkvr[off + lane]      = __float2bfloat16(r1 * sc);
        qkvr[off + 64 + lane] = __float2bfloat16(r2 * sc);
    }
}

// ---------------- MFMA flash attention, sliding window ----------------
// Block: 64 queries of one (b,h) = 4 waves x 16 rows. K-tiles of 32 keys.
// qkv row layout: [q 0..2047 | k 2048..2559 | v 2560..3071]
__global__ __launch_bounds__(256) void attn_mfma(const bf16* __restrict__ qkv,
                                                 bf16* __restrict__ y,
                                                 const int* __restrict__ winp) {
    const int bid = blockIdx.x;
    const int qt = bid & 31;            // T/64 = 32 q-tiles
    const int h  = (bid >> 5) & 15;
    const int b  = bid >> 9;
    const int t0 = qt * 64;
    const int kvh = h >> 2;
    const int tid = threadIdx.x;
    const int lane = tid & 63;
    const int w = tid >> 6;
    const int window = winp[0];

    __shared__ __align__(16) bf16 Ks[32][136];   // keys x d (pad 8: 2-way on frag reads)
    __shared__ __align__(16) bf16 Vt[128][40];   // d x keys (transposed for PV B-operand)
    __shared__ __align__(16) bf16 Ps[4][16][40]; // per-wave P round-trip

    const int fr = lane & 15;
    const int kq = (lane >> 4) * 8;

    // Q fragments: rows t0 + w*16 + fr, 4 chunks of K=32
    short8 qf[4];
    {
        const bf16* qp = qkv + ((size_t)(b * TT) + t0 + w * 16 + fr) * NQKV + h * HDq;
#pragma unroll
        for (int c = 0; c < 4; ++c)
            qf[c] = *reinterpret_cast<const short8*>(&qp[c * 32 + kq]);
    }

    f32x4 acc[8];
#pragma unroll
    for (int n = 0; n < 8; ++n) acc[n] = f32x4{0.f, 0.f, 0.f, 0.f};
    float mrow[4] = {-1e30f, -1e30f, -1e30f, -1e30f};
    float lrow[4] = {0.f, 0.f, 0.f, 0.f};

    int s_lo = t0 - window; if (s_lo < 0) s_lo = 0; s_lo &= ~31;
    const int s_hi = t0 + 63;

    const int str = tid & 31;          // staging key row
    const int stc = (tid >> 5) * 16;   // staging d chunk

    for (int sk = s_lo; sk <= s_hi; sk += 32) {
        __syncthreads();
        {
            const bf16* kp = qkv + ((size_t)(b * TT) + sk + str) * NQKV + 2048 + kvh * HDq;
            short8 k0 = *reinterpret_cast<const short8*>(&kp[stc]);
            short8 k1 = *reinterpret_cast<const short8*>(&kp[stc + 8]);
            *reinterpret_cast<short8*>(&Ks[str][stc])     = k0;
            *reinterpret_cast<short8*>(&Ks[str][stc + 8]) = k1;
            const bf16* vp = kp + 512;
            short8 v0 = *reinterpret_cast<const short8*>(&vp[stc]);
            short8 v1 = *reinterpret_cast<const short8*>(&vp[stc + 8]);
#pragma unroll
            for (int j = 0; j < 8; ++j) {
                *(ushort*)&Vt[stc + j][str]     = (ushort)v0[j];
                *(ushort*)&Vt[stc + 8 + j][str] = (ushort)v1[j];
            }
        }
        __syncthreads();

        // QK^T: S[16 q x 32 s] per wave
        f32x4 S0 = f32x4{0.f, 0.f, 0.f, 0.f}, S1 = f32x4{0.f, 0.f, 0.f, 0.f};
#pragma unroll
        for (int c = 0; c < 4; ++c) {
            short8 k0 = *reinterpret_cast<const short8*>(&Ks[fr][c * 32 + kq]);
            short8 k1 = *reinterpret_cast<const short8*>(&Ks[16 + fr][c * 32 + kq]);
            S0 = MFMA16(qf[c], k0, S0);
            S1 = MFMA16(qf[c], k1, S1);
        }

        // online softmax; C-layout: col = lane&15 (key), row = (lane>>4)*4 + j (query)
        const int rt = t0 + w * 16 + (lane >> 4) * 4;  // + j
        const int c0 = sk + fr, c1 = c0 + 16;
        const float scale = 0.08838834764831845f;
#pragma unroll
        for (int j = 0; j < 4; ++j) {
            int r = rt + j;
            bool ok0 = (c0 <= r) && (r - c0 <= window);
            bool ok1 = (c1 <= r) && (r - c1 <= window);
            float s0 = ok0 ? S0[j] * scale : -1e30f;
            float s1 = ok1 ? S1[j] * scale : -1e30f;
            float mj = fmaxf(s0, s1);
#pragma unroll
            for (int mm = 1; mm < 16; mm <<= 1) mj = fmaxf(mj, __shfl_xor(mj, mm));
            float nm = fmaxf(mrow[j], mj);
            float corr = __expf(mrow[j] - nm);
            float p0 = ok0 ? __expf(s0 - nm) : 0.f;
            float p1 = ok1 ? __expf(s1 - nm) : 0.f;
            mrow[j] = nm;
            float ps = p0 + p1;
#pragma unroll
            for (int mm = 1; mm < 16; mm <<= 1) ps += __shfl_xor(ps, mm);
            lrow[j] = lrow[j] * corr + ps;
#pragma unroll
            for (int n = 0; n < 8; ++n) acc[n][j] *= corr;
            int rl = (lane >> 4) * 4 + j;
            *(ushort*)&Ps[w][rl][fr]      = __bfloat16_as_ushort(__float2bfloat16(p0));
            *(ushort*)&Ps[w][rl][16 + fr] = __bfloat16_as_ushort(__float2bfloat16(p1));
        }

        // PV: O[16 q x 128 d] += P[16x32] * V[32x128]
        short8 pa = *reinterpret_cast<const short8*>(&Ps[w][fr][kq]);
#pragma unroll
        for (int n = 0; n < 8; ++n) {
            short8 vb = *reinterpret_cast<const short8*>(&Vt[n * 16 + fr][kq]);
            acc[n] = MFMA16(pa, vb, acc[n]);
        }
    }

    // epilogue: normalize + write
    const int rt = t0 + w * 16 + (lane >> 4) * 4;
#pragma unroll
    for (int j = 0; j < 4; ++j) {
        float inv = 1.f / lrow[j];
        bf16* yr = y + ((size_t)(b * TT) + rt + j) * CC + h * HDq;
#pragma unroll
        for (int n = 0; n < 8; ++n)
            yr[n * 16 + fr] = __float2bfloat16(acc[n][j] * inv);
    }
}

extern "C" void kernel_launch(void* const* d_in, const int* in_sizes, int n_in,
                              void* d_out, int out_size, void* d_ws, size_t ws_size,
                              hipStream_t stream) {
    const float* x     = (const float*)d_in[0];
    const float* ve    = (const float*)d_in[1];
    const float* cosb  = (const float*)d_in[2];
    const float* sinb  = (const float*)d_in[3];
    const float* Wq    = (const float*)d_in[4];
    const float* Wk    = (const float*)d_in[5];
    const float* Wv    = (const float*)d_in[6];
    const float* Wproj = (const float*)d_in[7];
    const float* Wgate = (const float*)d_in[8];
    const int*   winp  = (const int*)d_in[9];

    bf16* xb     = (bf16*)d_ws;
    bf16* wqkvb  = xb + (size_t)ROWS * CC;
    bf16* wprojb = wqkvb + (size_t)NQKV * CC;
    bf16* qkvb   = wprojb + (size_t)CC * CC;
    bf16* yb     = xb;   // alias: xb dead after qkv GEMM

    {
        int n4;
        n4 = ROWS * CC / 4;      cast_bf16<<<(n4 + 255) / 256, 256, 0, stream>>>(x, xb, n4);
        n4 = NHq * HDq * CC / 4; cast_bf16<<<(n4 + 255) / 256, 256, 0, stream>>>(Wq, wqkvb, n4);
        n4 = NKVq * HDq * CC / 4;
        cast_bf16<<<(n4 + 255) / 256, 256, 0, stream>>>(Wk, wqkvb + (size_t)NHq * HDq * CC, n4);
        cast_bf16<<<(n4 + 255) / 256, 256, 0, stream>>>(Wv, wqkvb + (size_t)(NHq + NKVq) * HDq * CC, n4);
        n4 = CC * CC / 4;        cast_bf16<<<(n4 + 255) / 256, 256, 0, stream>>>(Wproj, wprojb, n4);
    }

    // qkv = x @ [Wq;Wk;Wv]^T
    gemm_bt<0><<<dim3(ROWS / 128, NQKV / 128), 256, 0, stream>>>(xb, wqkvb, qkvb, ROWS, NQKV, CC);

    // gate/ve add + RoPE + RMSNorm (in place)
    postproc<<<ROWS, 256, 0, stream>>>(x, ve, cosb, sinb, Wgate, qkvb);

    // MFMA flash attention -> yb
    attn_mfma<<<BB * NHq * (TT / 64), 256, 0, stream>>>(qkvb, yb, winp);

    // out = y @ Wproj^T (fp32 out)
    gemm_bt<1><<<dim3(ROWS / 128, CC / 128), 256, 0, stream>>>(yb, wprojb, d_out, ROWS, CC, CC);
}